// Round 10
// baseline (306.344 us; speedup 1.0000x reference)
//
#include <hip/hip_runtime.h>
#include <stdint.h>

typedef __attribute__((ext_vector_type(8))) short short8;
typedef __attribute__((ext_vector_type(4))) short short4v;
typedef __attribute__((ext_vector_type(4))) float f32x4;

#define MFMA(a,b,c) __builtin_amdgcn_mfma_f32_16x16x32_bf16((a),(b),(c),0,0,0)
#define QSCALE 0.18033688f   /* 0.125 * log2(e): softmax in exp2 domain */
#define VT_LD 584
#define NTOK 577
#define PT_LD 72
#define AS1 __attribute__((address_space(1)))
#define AS3 __attribute__((address_space(3)))

__device__ __forceinline__ unsigned short f2bf(float f) {
    unsigned int u = __float_as_uint(f);
    u += 0x7fffu + ((u >> 16) & 1u);   // RNE
    return (unsigned short)(u >> 16);
}
__device__ __forceinline__ float bf2f(unsigned short u) {
    return __uint_as_float(((unsigned int)u) << 16);
}
__device__ __forceinline__ unsigned int cvt_pk_bf16(float lo, float hi) {
    unsigned int r;
    asm("v_cvt_pk_bf16_f32 %0, %1, %2" : "=v"(r) : "v"(lo), "v"(hi));
    return r;
}

// ---------------- conversions ----------------
__global__ __launch_bounds__(256) void cvt_f32_bf16(const float* __restrict__ in,
                                                    unsigned short* __restrict__ out, int n4) {
    int i = blockIdx.x * 256 + threadIdx.x;
    if (i < n4) {
        float4 v = ((const float4*)in)[i];
        short4v s;
        s[0] = (short)f2bf(v.x); s[1] = (short)f2bf(v.y);
        s[2] = (short)f2bf(v.z); s[3] = (short)f2bf(v.w);
        ((short4v*)out)[i] = s;
    }
}

// in [R][C] f32 -> out [C][R] bf16   (R,C multiples of 32)
__global__ __launch_bounds__(256) void transpose_cvt(const float* __restrict__ in,
                                                     unsigned short* __restrict__ out,
                                                     int R, int C) {
    __shared__ float tile[32][33];
    int c0 = blockIdx.x * 32, r0 = blockIdx.y * 32;
    int lc = threadIdx.x & 31, lr = threadIdx.x >> 5;
    #pragma unroll
    for (int i = 0; i < 4; ++i) {
        int r = lr + i * 8;
        tile[r][lc] = in[(size_t)(r0 + r) * C + c0 + lc];
    }
    __syncthreads();
    #pragma unroll
    for (int i = 0; i < 4; ++i) {
        int r = lr + i * 8;
        out[(size_t)(c0 + r) * R + r0 + lc] = f2bf(tile[lc][r]);
    }
}

// ---- GEMM: 256x256 tile, BK=64, 8 waves (2Mx4N), 2 K-tile LDS buffers (128KB) ----
// Stage(kt+1) at iter start -> full-iteration latency cover; one vmcnt+barrier per
// K-tile. 128B row stride + XOR chunk swizzle (R2/R6-proven: 0 bank conflicts).
template<int EPI>
__global__ __launch_bounds__(512, 2) void gemm256(
    const unsigned short* __restrict__ A,
    const unsigned short* __restrict__ Bt,
    const float* __restrict__ bias,
    unsigned short* __restrict__ q_out, unsigned short* __restrict__ k_out,
    unsigned short* __restrict__ vt_out, float* __restrict__ f_out,
    int M, int NB)
{
    __shared__ __align__(16) unsigned short As[2][256 * 64];
    __shared__ __align__(16) unsigned short Bs[2][256 * 64];

    // bijective XCD swizzle (m204)
    const int nwg = gridDim.x, orig = blockIdx.x;
    const int qd = nwg >> 3, r8 = nwg & 7;
    const int xcd = orig & 7, j = orig >> 3;
    const int wg = (xcd < r8 ? xcd * (qd + 1) : r8 * (qd + 1) + (xcd - r8) * qd) + j;
    const int bx = wg % NB, by = wg / NB;
    const int m0 = by * 256, n0 = bx * 256;

    const int t = threadIdx.x, lane = t & 63, w = t >> 6;
    const int g = lane >> 4, c = lane & 15;
    const int wr = w >> 2, wcn = w & 3;            // 2 x 4 wave grid
    const int srow = t >> 3;                       // 0..63 (staging row within 64-chunk)
    const int csw = (((t & 7) ^ (srow & 7)) * 8);  // pre-swizzled source chunk

    f32x4 acc[8][4] = {};

    auto stage = [&](int buf, int kt) {
        const int k0 = kt * 64;
        #pragma unroll
        for (int i = 0; i < 4; ++i) {
            int row = i * 64 + srow;
            int ra = m0 + row; ra = ra < M ? ra : M - 1;
            __builtin_amdgcn_global_load_lds(
                (const AS1 unsigned int*)&A[(size_t)ra * 768 + k0 + csw],
                (AS3 unsigned int*)&As[buf][i * 4096 + w * 512], 16, 0, 0);
            __builtin_amdgcn_global_load_lds(
                (const AS1 unsigned int*)&Bt[(size_t)(n0 + row) * 768 + k0 + csw],
                (AS3 unsigned int*)&Bs[buf][i * 4096 + w * 512], 16, 0, 0);
        }
    };
    auto compute = [&](int buf) {
        #pragma unroll
        for (int kk = 0; kk < 2; ++kk) {
            short8 af[8], bfv[4];
            #pragma unroll
            for (int mf = 0; mf < 8; ++mf) {
                int rr = wr * 128 + mf * 16 + c;
                af[mf] = *(const short8*)&As[buf][rr * 64 + (((kk * 4 + g) ^ (c & 7)) * 8)];
            }
            #pragma unroll
            for (int nf = 0; nf < 4; ++nf) {
                int rr = wcn * 64 + nf * 16 + c;
                bfv[nf] = *(const short8*)&Bs[buf][rr * 64 + (((kk * 4 + g) ^ (c & 7)) * 8)];
            }
            __builtin_amdgcn_s_setprio(1);
            #pragma unroll
            for (int mf = 0; mf < 8; ++mf)
            #pragma unroll
            for (int nf = 0; nf < 4; ++nf)
                acc[mf][nf] = MFMA(af[mf], bfv[nf], acc[mf][nf]);
            __builtin_amdgcn_s_setprio(0);
        }
    };

    stage(0, 0);
    asm volatile("s_waitcnt vmcnt(0)" ::: "memory");
    __builtin_amdgcn_s_barrier();
    __builtin_amdgcn_sched_barrier(0);

    #pragma unroll
    for (int kt = 0; kt < 12; ++kt) {
        if (kt < 11) stage((kt + 1) & 1, kt + 1);   // issue-early: full iter of cover
        compute(kt & 1);
        __builtin_amdgcn_sched_barrier(0);
        asm volatile("s_waitcnt vmcnt(0)" ::: "memory");  // exact: only kt+1's loads in flight
        __builtin_amdgcn_s_barrier();
        __builtin_amdgcn_sched_barrier(0);
    }

    #pragma unroll
    for (int mf = 0; mf < 8; ++mf)
    #pragma unroll
    for (int nf = 0; nf < 4; ++nf) {
        int n = n0 + wcn * 64 + nf * 16 + c;
        float bv = bias[n];
        #pragma unroll
        for (int e = 0; e < 4; ++e) {
            int m = m0 + wr * 128 + mf * 16 + g * 4 + e;
            if (m >= M) continue;
            float v = acc[mf][nf][e] + bv;
            if (EPI == 0) {
                int which = n / 768;
                int rr = n - which * 768;
                int h = rr >> 6, d = rr & 63;
                int b = m / 577, tok = m - b * 577;
                int bh = b * 12 + h;
                if (which == 0)      q_out[((size_t)bh * 577 + tok) * 64 + d] = f2bf(v * QSCALE);
                else if (which == 1) k_out[((size_t)bh * 577 + tok) * 64 + d] = f2bf(v);
                else                 vt_out[((size_t)bh * 64 + d) * VT_LD + tok] = f2bf(v);
            } else {
                f_out[(size_t)m * 768 + n] = v;
            }
        }
    }
}

// ---------------- flash attention: LDS-staged K/V (2-phase dbuf), fixed-shift softmax --
// Q(pre-scaled),K: [B*H][577][64] bf16 ; Vt: [B*H][64][584] bf16 ; O: [B*577][768] bf16
__global__ __launch_bounds__(256, 3) void attn_flash(
    const unsigned short* __restrict__ Qg,
    const unsigned short* __restrict__ Kg,
    const unsigned short* __restrict__ Vtg,
    unsigned short* __restrict__ Og)
{
    __shared__ __align__(16) unsigned short KL[2][64][64];
    __shared__ __align__(16) unsigned short VL[2][64][64];
    __shared__ __align__(16) unsigned short pt[4][16][PT_LD];

    const int nwg = gridDim.x, orig = blockIdx.x;
    const int qd = nwg >> 3, jj8 = nwg & 7;
    const int xcd = orig & 7, jj = orig >> 3;
    const int wgid = (xcd < jj8 ? xcd * (qd + 1) : jj8 * (qd + 1) + (xcd - jj8) * qd) + jj;
    const int qt = wgid % 10;
    const int bh = wgid / 10;
    const int b = bh / 12, h = bh - b * 12;
    const int t = threadIdx.x, w = t >> 6, lane = t & 63;
    const int g = lane >> 4, c = lane & 15;
    const int rowi = t >> 3;                        // 0..31
    const int gch = ((t & 7) ^ (rowi & 7)) * 8;     // pre-swizzled source chunk

    const unsigned short* Qh = Qg + (size_t)bh * NTOK * 64;
    const unsigned short* Kh = Kg + (size_t)bh * NTOK * 64;
    const unsigned short* Vh = Vtg + (size_t)bh * 64 * VT_LD;

    const int q = qt * 64 + w * 16 + c;
    const int qc = q < NTOK ? q : NTOK - 1;

    short8 bq0 = *(const short8*)&Qh[(size_t)qc * 64 +      g * 8];
    short8 bq1 = *(const short8*)&Qh[(size_t)qc * 64 + 32 + g * 8];

    auto stage = [&](int buf, int kbase) {
        #pragma unroll
        for (int i = 0; i < 2; ++i) {
            __builtin_amdgcn_global_load_lds(
                (const AS1 unsigned int*)&Kh[(size_t)(kbase + i * 32 + rowi) * 64 + gch],
                (AS3 unsigned int*)(&KL[buf][0][0] + (i * 256 + w * 64) * 8), 16, 0, 0);
            __builtin_amdgcn_global_load_lds(
                (const AS1 unsigned int*)&Vh[(size_t)(i * 32 + rowi) * VT_LD + kbase + gch],
                (AS3 unsigned int*)(&VL[buf][0][0] + (i * 256 + w * 64) * 8), 16, 0, 0);
        }
    };

    f32x4 lsumv = {};
    f32x4 ot[4] = {};

    stage(0, 0);
    __syncthreads();

    int cur = 0;
    for (int kt = 0; kt < 9; ++kt) {
        if (kt < 8) stage(cur ^ 1, (kt + 1) * 64);
        // K fragments from LDS (swizzled read, ~2-way)
        short8 kf0[4], kf1[4];
        #pragma unroll
        for (int f = 0; f < 4; ++f) {
            const unsigned short* kr = &KL[cur][f * 16 + c][0];
            kf0[f] = *(const short8*)&kr[((g    ) ^ (c & 7)) * 8];
            kf1[f] = *(const short8*)&kr[((4 + g) ^ (c & 7)) * 8];
        }
        f32x4 st[4];
        __builtin_amdgcn_s_setprio(1);
        #pragma unroll
        for (int f = 0; f < 4; ++f) {
            f32x4 z = {};
            z = MFMA(kf0[f], bq0, z);
            z = MFMA(kf1[f], bq1, z);
            st[f] = z;
        }
        __builtin_amdgcn_s_setprio(0);
        #pragma unroll
        for (int f = 0; f < 4; ++f) {
            float p0 = exp2f(fminf(st[f][0], 60.f));
            float p1 = exp2f(fminf(st[f][1], 60.f));
            float p2 = exp2f(fminf(st[f][2], 60.f));
            float p3 = exp2f(fminf(st[f][3], 60.f));
            lsumv[0] += p0; lsumv[1] += p1; lsumv[2] += p2; lsumv[3] += p3;
            uint2 pw;
            pw.x = cvt_pk_bf16(p0, p1);
            pw.y = cvt_pk_bf16(p2, p3);
            *(uint2*)&pt[w][c][f * 16 + g * 4] = pw;
        }
        __builtin_amdgcn_s_setprio(1);
        #pragma unroll
        for (int kk = 0; kk < 2; ++kk) {
            short8 bp = *(const short8*)&pt[w][c][kk * 32 + g * 8];
            #pragma unroll
            for (int df = 0; df < 4; ++df) {
                const unsigned short* vr = &VL[cur][df * 16 + c][0];
                short8 av = *(const short8*)&vr[((kk * 4 + g) ^ (c & 7)) * 8];
                ot[df] = MFMA(av, bp, ot[df]);
            }
        }
        __builtin_amdgcn_s_setprio(0);
        __syncthreads();   // drains vmcnt: next tile staged & this tile's reads done
        cur ^= 1;
    }

    float lsum = (lsumv[0] + lsumv[1]) + (lsumv[2] + lsumv[3]);
    lsum += __shfl_xor(lsum, 16);
    lsum += __shfl_xor(lsum, 32);

    // tail: key 576 (scalar)
    {
        const unsigned short* kp = &Kh[(size_t)576 * 64];
        float dot = 0.f;
        #pragma unroll
        for (int jx = 0; jx < 8; ++jx) {
            dot += bf2f((unsigned short)bq0[jx]) * bf2f(kp[g * 8 + jx]);
            dot += bf2f((unsigned short)bq1[jx]) * bf2f(kp[32 + g * 8 + jx]);
        }
        dot += __shfl_xor(dot, 16);
        dot += __shfl_xor(dot, 32);
        float p = exp2f(fminf(dot, 60.f));
        lsum += p;
        #pragma unroll
        for (int df = 0; df < 4; ++df)
        #pragma unroll
        for (int e = 0; e < 4; ++e)
            ot[df][e] += p * bf2f(Vh[(size_t)(df * 16 + g * 4 + e) * VT_LD + 576]);
    }

    float inv = 1.0f / lsum;
    if (q < NTOK) {
        size_t orow = ((size_t)b * NTOK + q) * 768 + h * 64;
        #pragma unroll
        for (int df = 0; df < 4; ++df) {
            uint2 ov;
            ov.x = cvt_pk_bf16(ot[df][0] * inv, ot[df][1] * inv);
            ov.y = cvt_pk_bf16(ot[df][2] * inv, ot[df][3] * inv);
            *(uint2*)&Og[orow + df * 16 + g * 4] = ov;
        }
    }
}

// ---------------- launch ----------------
extern "C" void kernel_launch(void* const* d_in, const int* in_sizes, int n_in,
                              void* d_out, int out_size, void* d_ws, size_t ws_size,
                              hipStream_t stream) {
    const float* x      = (const float*)d_in[0];
    const float* W_qkv  = (const float*)d_in[1];
    const float* b_qkv  = (const float*)d_in[2];
    const float* W_proj = (const float*)d_in[3];
    const float* b_proj = (const float*)d_in[4];
    float* out = (float*)d_out;

    const int B = 32, N = 577, C = 768, H = 12;
    const int M = B * N;            // 18464

    char* ws = (char*)d_ws;
    size_t off = 0;
    auto alloc = [&](size_t bytes) {
        char* p = ws + off;
        off += (bytes + 255) & ~(size_t)255;
        return p;
    };
    unsigned short* xb    = (unsigned short*)alloc((size_t)M * C * 2);
    unsigned short* wqkvt = (unsigned short*)alloc((size_t)3 * C * C * 2);
    unsigned short* wprjt = (unsigned short*)alloc((size_t)C * C * 2);
    unsigned short* Qb    = (unsigned short*)alloc((size_t)B * H * N * 64 * 2);
    unsigned short* Kb    = (unsigned short*)alloc((size_t)B * H * N * 64 * 2);
    unsigned short* Vtb   = (unsigned short*)alloc((size_t)B * H * 64 * VT_LD * 2);
    unsigned short* attn  = xb;     // x_bf16 dead after QKV GEMM

    int n4 = M * C / 4;
    cvt_f32_bf16<<<dim3((n4 + 255) / 256), 256, 0, stream>>>(x, xb, n4);
    transpose_cvt<<<dim3(3 * C / 32, C / 32), 256, 0, stream>>>(W_qkv, wqkvt, C, 3 * C);
    transpose_cvt<<<dim3(C / 32, C / 32), 256, 0, stream>>>(W_proj, wprjt, C, C);

    gemm256<0><<<dim3(73 * 9), 512, 0, stream>>>(
        xb, wqkvt, b_qkv, Qb, Kb, Vtb, nullptr, M, 9);

    attn_flash<<<dim3(3840), 256, 0, stream>>>(Qb, Kb, Vtb, attn);

    gemm256<1><<<dim3(73 * 3), 512, 0, stream>>>(
        attn, wprjt, b_proj, nullptr, nullptr, nullptr, out, M, 3);
}

// Round 11
// 247.031 us; speedup vs baseline: 1.2401x; 1.2401x over previous
//
#include <hip/hip_runtime.h>
#include <stdint.h>

typedef __attribute__((ext_vector_type(8))) short short8;
typedef __attribute__((ext_vector_type(4))) short short4v;
typedef __attribute__((ext_vector_type(4))) float f32x4;

#define MFMA(a,b,c) __builtin_amdgcn_mfma_f32_16x16x32_bf16((a),(b),(c),0,0,0)
#define QSCALE 0.18033688f   /* 0.125 * log2(e): softmax in exp2 domain */
#define VT_LD 584
#define NTOK 577
#define PT_LD 72
#define AS1 __attribute__((address_space(1)))
#define AS3 __attribute__((address_space(3)))

__device__ __forceinline__ unsigned short f2bf(float f) {
    unsigned int u = __float_as_uint(f);
    u += 0x7fffu + ((u >> 16) & 1u);   // RNE
    return (unsigned short)(u >> 16);
}
__device__ __forceinline__ float bf2f(unsigned short u) {
    return __uint_as_float(((unsigned int)u) << 16);
}
__device__ __forceinline__ unsigned int cvt_pk_bf16(float lo, float hi) {
    unsigned int r;
    asm("v_cvt_pk_bf16_f32 %0, %1, %2" : "=v"(r) : "v"(lo), "v"(hi));
    return r;
}

// ---------------- conversions ----------------
__global__ __launch_bounds__(256) void cvt_f32_bf16(const float* __restrict__ in,
                                                    unsigned short* __restrict__ out, int n4) {
    int i = blockIdx.x * 256 + threadIdx.x;
    if (i < n4) {
        float4 v = ((const float4*)in)[i];
        short4v s;
        s[0] = (short)f2bf(v.x); s[1] = (short)f2bf(v.y);
        s[2] = (short)f2bf(v.z); s[3] = (short)f2bf(v.w);
        ((short4v*)out)[i] = s;
    }
}

// in [R][C] f32 -> out [C][R] bf16   (R,C multiples of 32)
__global__ __launch_bounds__(256) void transpose_cvt(const float* __restrict__ in,
                                                     unsigned short* __restrict__ out,
                                                     int R, int C) {
    __shared__ float tile[32][33];
    int c0 = blockIdx.x * 32, r0 = blockIdx.y * 32;
    int lc = threadIdx.x & 31, lr = threadIdx.x >> 5;
    #pragma unroll
    for (int i = 0; i < 4; ++i) {
        int r = lr + i * 8;
        tile[r][lc] = in[(size_t)(r0 + r) * C + c0 + lc];
    }
    __syncthreads();
    #pragma unroll
    for (int i = 0; i < 4; ++i) {
        int r = lr + i * 8;
        out[(size_t)(c0 + r) * R + r0 + lc] = f2bf(tile[lc][r]);
    }
}

// ---- GEMM A (QKV): 256x128 tile, 512 thr (4Mx2N waves), single-buffer 2-phase ----
// R6-proven skeleton: stage -> sync -> compute -> sync. 48KB LDS -> ~3 blocks/CU.
// XOR swizzle, 128B row stride (0 conflicts, R2/R6-verified).
template<int EPI>
__global__ __launch_bounds__(512) void gemm256x128(
    const unsigned short* __restrict__ A,
    const unsigned short* __restrict__ Bt,
    const float* __restrict__ bias,
    unsigned short* __restrict__ q_out, unsigned short* __restrict__ k_out,
    unsigned short* __restrict__ vt_out, float* __restrict__ f_out,
    int M, int NB)
{
    __shared__ __align__(16) unsigned short As[256 * 64];
    __shared__ __align__(16) unsigned short Bs[128 * 64];

    const int nwg = gridDim.x, orig = blockIdx.x;
    const int qd = nwg >> 3, r8 = nwg & 7;
    const int xcd = orig & 7, j = orig >> 3;
    const int wg = (xcd < r8 ? xcd * (qd + 1) : r8 * (qd + 1) + (xcd - r8) * qd) + j;
    const int bx = wg % NB, by = wg / NB;
    const int m0 = by * 256, n0 = bx * 128;

    const int t = threadIdx.x, lane = t & 63, w = t >> 6;
    const int g = lane >> 4, c = lane & 15;
    const int wr = w >> 1, wcn = w & 1;            // 4 x 2 wave grid
    const int srow = t >> 3;                       // 0..63
    const int csw = (((t & 7) ^ (srow & 7)) * 8);  // pre-swizzled source chunk

    f32x4 acc[4][4] = {};

    for (int k0 = 0; k0 < 768; k0 += 64) {
        #pragma unroll
        for (int i = 0; i < 4; ++i) {              // A: 256 rows in 4 passes
            int row = i * 64 + srow;
            int ra = m0 + row; ra = ra < M ? ra : M - 1;
            __builtin_amdgcn_global_load_lds(
                (const AS1 unsigned int*)&A[(size_t)ra * 768 + k0 + csw],
                (AS3 unsigned int*)&As[i * 4096 + w * 512], 16, 0, 0);
        }
        #pragma unroll
        for (int i = 0; i < 2; ++i) {              // B: 128 rows in 2 passes
            int row = i * 64 + srow;
            __builtin_amdgcn_global_load_lds(
                (const AS1 unsigned int*)&Bt[(size_t)(n0 + row) * 768 + k0 + csw],
                (AS3 unsigned int*)&Bs[i * 4096 + w * 512], 16, 0, 0);
        }
        __syncthreads();
        #pragma unroll
        for (int kk = 0; kk < 2; ++kk) {
            short8 af[4], bfv[4];
            #pragma unroll
            for (int mf = 0; mf < 4; ++mf) {
                int rr = wr * 64 + mf * 16 + c;
                af[mf] = *(const short8*)&As[rr * 64 + (((kk * 4 + g) ^ (c & 7)) * 8)];
            }
            #pragma unroll
            for (int nf = 0; nf < 4; ++nf) {
                int rr = wcn * 64 + nf * 16 + c;
                bfv[nf] = *(const short8*)&Bs[rr * 64 + (((kk * 4 + g) ^ (c & 7)) * 8)];
            }
            __builtin_amdgcn_s_setprio(1);
            #pragma unroll
            for (int mf = 0; mf < 4; ++mf)
            #pragma unroll
            for (int nf = 0; nf < 4; ++nf)
                acc[mf][nf] = MFMA(af[mf], bfv[nf], acc[mf][nf]);
            __builtin_amdgcn_s_setprio(0);
        }
        __syncthreads();
    }

    #pragma unroll
    for (int mf = 0; mf < 4; ++mf)
    #pragma unroll
    for (int nf = 0; nf < 4; ++nf) {
        int n = n0 + wcn * 64 + nf * 16 + c;
        float bv = bias[n];
        #pragma unroll
        for (int e = 0; e < 4; ++e) {
            int m = m0 + wr * 64 + mf * 16 + g * 4 + e;
            if (m >= M) continue;
            float v = acc[mf][nf][e] + bv;
            if (EPI == 0) {
                int which = n / 768;
                int rr = n - which * 768;
                int h = rr >> 6, d = rr & 63;
                int b = m / 577, tok = m - b * 577;
                int bh = b * 12 + h;
                if (which == 0)      q_out[((size_t)bh * 577 + tok) * 64 + d] = f2bf(v * QSCALE);
                else if (which == 1) k_out[((size_t)bh * 577 + tok) * 64 + d] = f2bf(v);
                else                 vt_out[((size_t)bh * 64 + d) * VT_LD + tok] = f2bf(v);
            } else {
                f_out[(size_t)m * 768 + n] = v;
            }
        }
    }
}

// ---- GEMM B (proj): R6 128x128 single-buffer 2-phase (proven 52us) ----
template<int EPI>
__global__ __launch_bounds__(256) void gemm128(
    const unsigned short* __restrict__ A,
    const unsigned short* __restrict__ Bt,
    const float* __restrict__ bias,
    unsigned short* __restrict__ q_out, unsigned short* __restrict__ k_out,
    unsigned short* __restrict__ vt_out, float* __restrict__ f_out,
    int M, int K, int NB)
{
    __shared__ __align__(16) unsigned short As[128 * 64];
    __shared__ __align__(16) unsigned short Bs[128 * 64];

    const int nwg = gridDim.x, orig = blockIdx.x;
    const int qd = nwg >> 3, r = nwg & 7;
    const int xcd = orig & 7, j = orig >> 3;
    const int wg = (xcd < r ? xcd * (qd + 1) : r * (qd + 1) + (xcd - r) * qd) + j;
    const int bx = wg % NB, by = wg / NB;
    const int m0 = by * 128, n0 = bx * 128;

    const int t = threadIdx.x, lane = t & 63, w = t >> 6;
    const int g = lane >> 4, c = lane & 15;
    const int wr = w >> 1, wc = w & 1;
    const int rowi = t >> 3;
    const int csw = (((t & 7) ^ (rowi & 7)) * 8);

    f32x4 acc[4][4] = {};

    for (int k0 = 0; k0 < K; k0 += 64) {
        #pragma unroll
        for (int i = 0; i < 4; ++i) {
            int row = i * 32 + rowi;
            int ra = m0 + row; ra = ra < M ? ra : M - 1;
            __builtin_amdgcn_global_load_lds(
                (const AS1 unsigned int*)&A[(size_t)ra * K + k0 + csw],
                (AS3 unsigned int*)&As[(i * 256 + w * 64) * 8], 16, 0, 0);
            __builtin_amdgcn_global_load_lds(
                (const AS1 unsigned int*)&Bt[(size_t)(n0 + row) * K + k0 + csw],
                (AS3 unsigned int*)&Bs[(i * 256 + w * 64) * 8], 16, 0, 0);
        }
        __syncthreads();
        #pragma unroll
        for (int kk = 0; kk < 2; ++kk) {
            short8 af[4], bfr[4];
            #pragma unroll
            for (int mf = 0; mf < 4; ++mf) {
                int rr = wr * 64 + mf * 16 + c;
                af[mf] = *(const short8*)&As[rr * 64 + (((kk * 4 + g) ^ (c & 7)) * 8)];
            }
            #pragma unroll
            for (int nf = 0; nf < 4; ++nf) {
                int rr = wc * 64 + nf * 16 + c;
                bfr[nf] = *(const short8*)&Bs[rr * 64 + (((kk * 4 + g) ^ (c & 7)) * 8)];
            }
            __builtin_amdgcn_s_setprio(1);
            #pragma unroll
            for (int mf = 0; mf < 4; ++mf)
            #pragma unroll
            for (int nf = 0; nf < 4; ++nf)
                acc[mf][nf] = MFMA(af[mf], bfr[nf], acc[mf][nf]);
            __builtin_amdgcn_s_setprio(0);
        }
        __syncthreads();
    }

    #pragma unroll
    for (int mf = 0; mf < 4; ++mf)
    #pragma unroll
    for (int nf = 0; nf < 4; ++nf) {
        int n = n0 + wc * 64 + nf * 16 + c;
        float bv = bias[n];
        #pragma unroll
        for (int e = 0; e < 4; ++e) {
            int m = m0 + wr * 64 + mf * 16 + g * 4 + e;
            if (m >= M) continue;
            float v = acc[mf][nf][e] + bv;
            if (EPI == 0) {
                int which = n / 768;
                int rr = n - which * 768;
                int h = rr >> 6, d = rr & 63;
                int b = m / 577, tok = m - b * 577;
                int bh = b * 12 + h;
                if (which == 0)      q_out[((size_t)bh * 577 + tok) * 64 + d] = f2bf(v * QSCALE);
                else if (which == 1) k_out[((size_t)bh * 577 + tok) * 64 + d] = f2bf(v);
                else                 vt_out[((size_t)bh * 64 + d) * VT_LD + tok] = f2bf(v);
            } else {
                f_out[(size_t)m * 768 + n] = v;
            }
        }
    }
}

// ---------------- flash attention: LDS-staged K/V (2-phase dbuf), fixed-shift softmax --
// Q(pre-scaled),K: [B*H][577][64] bf16 ; Vt: [B*H][64][584] bf16 ; O: [B*577][768] bf16
__global__ __launch_bounds__(256, 3) void attn_flash(
    const unsigned short* __restrict__ Qg,
    const unsigned short* __restrict__ Kg,
    const unsigned short* __restrict__ Vtg,
    unsigned short* __restrict__ Og)
{
    __shared__ __align__(16) unsigned short KL[2][64][64];
    __shared__ __align__(16) unsigned short VL[2][64][64];
    __shared__ __align__(16) unsigned short pt[4][16][PT_LD];

    const int nwg = gridDim.x, orig = blockIdx.x;
    const int qd = nwg >> 3, jj8 = nwg & 7;
    const int xcd = orig & 7, jj = orig >> 3;
    const int wgid = (xcd < jj8 ? xcd * (qd + 1) : jj8 * (qd + 1) + (xcd - jj8) * qd) + jj;
    const int qt = wgid % 10;
    const int bh = wgid / 10;
    const int b = bh / 12, h = bh - b * 12;
    const int t = threadIdx.x, w = t >> 6, lane = t & 63;
    const int g = lane >> 4, c = lane & 15;
    const int rowi = t >> 3;                        // 0..31
    const int gch = ((t & 7) ^ (rowi & 7)) * 8;     // pre-swizzled source chunk

    const unsigned short* Qh = Qg + (size_t)bh * NTOK * 64;
    const unsigned short* Kh = Kg + (size_t)bh * NTOK * 64;
    const unsigned short* Vh = Vtg + (size_t)bh * 64 * VT_LD;

    const int q = qt * 64 + w * 16 + c;
    const int qc = q < NTOK ? q : NTOK - 1;

    short8 bq0 = *(const short8*)&Qh[(size_t)qc * 64 +      g * 8];
    short8 bq1 = *(const short8*)&Qh[(size_t)qc * 64 + 32 + g * 8];

    auto stage = [&](int buf, int kbase) {
        #pragma unroll
        for (int i = 0; i < 2; ++i) {
            __builtin_amdgcn_global_load_lds(
                (const AS1 unsigned int*)&Kh[(size_t)(kbase + i * 32 + rowi) * 64 + gch],
                (AS3 unsigned int*)(&KL[buf][0][0] + (i * 256 + w * 64) * 8), 16, 0, 0);
            __builtin_amdgcn_global_load_lds(
                (const AS1 unsigned int*)&Vh[(size_t)(i * 32 + rowi) * VT_LD + kbase + gch],
                (AS3 unsigned int*)(&VL[buf][0][0] + (i * 256 + w * 64) * 8), 16, 0, 0);
        }
    };

    f32x4 lsumv = {};
    f32x4 ot[4] = {};

    stage(0, 0);
    __syncthreads();

    int cur = 0;
    for (int kt = 0; kt < 9; ++kt) {
        if (kt < 8) stage(cur ^ 1, (kt + 1) * 64);
        short8 kf0[4], kf1[4];
        #pragma unroll
        for (int f = 0; f < 4; ++f) {
            const unsigned short* kr = &KL[cur][f * 16 + c][0];
            kf0[f] = *(const short8*)&kr[((g    ) ^ (c & 7)) * 8];
            kf1[f] = *(const short8*)&kr[((4 + g) ^ (c & 7)) * 8];
        }
        f32x4 st[4];
        __builtin_amdgcn_s_setprio(1);
        #pragma unroll
        for (int f = 0; f < 4; ++f) {
            f32x4 z = {};
            z = MFMA(kf0[f], bq0, z);
            z = MFMA(kf1[f], bq1, z);
            st[f] = z;
        }
        __builtin_amdgcn_s_setprio(0);
        #pragma unroll
        for (int f = 0; f < 4; ++f) {
            float p0 = exp2f(fminf(st[f][0], 60.f));
            float p1 = exp2f(fminf(st[f][1], 60.f));
            float p2 = exp2f(fminf(st[f][2], 60.f));
            float p3 = exp2f(fminf(st[f][3], 60.f));
            lsumv[0] += p0; lsumv[1] += p1; lsumv[2] += p2; lsumv[3] += p3;
            uint2 pw;
            pw.x = cvt_pk_bf16(p0, p1);
            pw.y = cvt_pk_bf16(p2, p3);
            *(uint2*)&pt[w][c][f * 16 + g * 4] = pw;
        }
        __builtin_amdgcn_s_setprio(1);
        #pragma unroll
        for (int kk = 0; kk < 2; ++kk) {
            short8 bp = *(const short8*)&pt[w][c][kk * 32 + g * 8];
            #pragma unroll
            for (int df = 0; df < 4; ++df) {
                const unsigned short* vr = &VL[cur][df * 16 + c][0];
                short8 av = *(const short8*)&vr[((kk * 4 + g) ^ (c & 7)) * 8];
                ot[df] = MFMA(av, bp, ot[df]);
            }
        }
        __builtin_amdgcn_s_setprio(0);
        __syncthreads();
        cur ^= 1;
    }

    float lsum = (lsumv[0] + lsumv[1]) + (lsumv[2] + lsumv[3]);
    lsum += __shfl_xor(lsum, 16);
    lsum += __shfl_xor(lsum, 32);

    // tail: key 576 (scalar)
    {
        const unsigned short* kp = &Kh[(size_t)576 * 64];
        float dot = 0.f;
        #pragma unroll
        for (int jx = 0; jx < 8; ++jx) {
            dot += bf2f((unsigned short)bq0[jx]) * bf2f(kp[g * 8 + jx]);
            dot += bf2f((unsigned short)bq1[jx]) * bf2f(kp[32 + g * 8 + jx]);
        }
        dot += __shfl_xor(dot, 16);
        dot += __shfl_xor(dot, 32);
        float p = exp2f(fminf(dot, 60.f));
        lsum += p;
        #pragma unroll
        for (int df = 0; df < 4; ++df)
        #pragma unroll
        for (int e = 0; e < 4; ++e)
            ot[df][e] += p * bf2f(Vh[(size_t)(df * 16 + g * 4 + e) * VT_LD + 576]);
    }

    float inv = 1.0f / lsum;
    if (q < NTOK) {
        size_t orow = ((size_t)b * NTOK + q) * 768 + h * 64;
        #pragma unroll
        for (int df = 0; df < 4; ++df) {
            uint2 ov;
            ov.x = cvt_pk_bf16(ot[df][0] * inv, ot[df][1] * inv);
            ov.y = cvt_pk_bf16(ot[df][2] * inv, ot[df][3] * inv);
            *(uint2*)&Og[orow + df * 16 + g * 4] = ov;
        }
    }
}

// ---------------- launch ----------------
extern "C" void kernel_launch(void* const* d_in, const int* in_sizes, int n_in,
                              void* d_out, int out_size, void* d_ws, size_t ws_size,
                              hipStream_t stream) {
    const float* x      = (const float*)d_in[0];
    const float* W_qkv  = (const float*)d_in[1];
    const float* b_qkv  = (const float*)d_in[2];
    const float* W_proj = (const float*)d_in[3];
    const float* b_proj = (const float*)d_in[4];
    float* out = (float*)d_out;

    const int B = 32, N = 577, C = 768, H = 12;
    const int M = B * N;            // 18464

    char* ws = (char*)d_ws;
    size_t off = 0;
    auto alloc = [&](size_t bytes) {
        char* p = ws + off;
        off += (bytes + 255) & ~(size_t)255;
        return p;
    };
    unsigned short* xb    = (unsigned short*)alloc((size_t)M * C * 2);
    unsigned short* wqkvt = (unsigned short*)alloc((size_t)3 * C * C * 2);
    unsigned short* wprjt = (unsigned short*)alloc((size_t)C * C * 2);
    unsigned short* Qb    = (unsigned short*)alloc((size_t)B * H * N * 64 * 2);
    unsigned short* Kb    = (unsigned short*)alloc((size_t)B * H * N * 64 * 2);
    unsigned short* Vtb   = (unsigned short*)alloc((size_t)B * H * 64 * VT_LD * 2);
    unsigned short* attn  = xb;     // x_bf16 dead after QKV GEMM

    int n4 = M * C / 4;
    cvt_f32_bf16<<<dim3((n4 + 255) / 256), 256, 0, stream>>>(x, xb, n4);
    transpose_cvt<<<dim3(3 * C / 32, C / 32), 256, 0, stream>>>(W_qkv, wqkvt, C, 3 * C);
    transpose_cvt<<<dim3(C / 32, C / 32), 256, 0, stream>>>(W_proj, wprjt, C, C);

    // QKV: 256x128 tiles, 73 x 18 = 1314 blocks
    gemm256x128<0><<<dim3(73 * 18), 512, 0, stream>>>(
        xb, wqkvt, b_qkv, Qb, Kb, Vtb, nullptr, M, 18);

    attn_flash<<<dim3(3840), 256, 0, stream>>>(Qb, Kb, Vtb, attn);

    // proj: 128x128 tiles (R6-proven), 145 x 6 = 870 blocks
    gemm128<1><<<dim3(6 * 145), 256, 0, stream>>>(
        attn, wprjt, b_proj, nullptr, nullptr, nullptr, out, M, C, 6);
}